// Round 9
// baseline (815.782 us; speedup 1.0000x reference)
//
#include <hip/hip_runtime.h>
#include <math.h>

#define DEPTH 6
#define HEADS 8
#define BB    2
#define NN    128
#define EE    160
#define NF    127
#define DIMM  128
#define INNER 512
#define NNODE (BB * NN)   // 256

__device__ __forceinline__ void fma4(float4& acc, float a, const float4 w) {
    acc.x += a * w.x; acc.y += a * w.y; acc.z += a * w.z; acc.w += a * w.w;
}

// 512-thread block: reduce within each 128-thread group (2 waves). Result valid
// per group. sbuf8: >=8 floats.
__device__ __forceinline__ float group_reduce_128(float v, float* sbuf8) {
#pragma unroll
    for (int off = 32; off > 0; off >>= 1) v += __shfl_xor(v, off, 64);
    int w = threadIdx.x >> 6;
    if ((threadIdx.x & 63) == 0) sbuf8[w] = v;
    __syncthreads();
    int g = threadIdx.x >> 7;
    float r = sbuf8[2 * g] + sbuf8[2 * g + 1];
    __syncthreads();
    return r;
}

// ---------- kernels ----------

// Warm weights into L3 (poison between replays evicts everything).
__global__ __launch_bounds__(512) void k_warm(const float* Wq, const float* Wkv,
                                              const float* Wo, const float* W1,
                                              const float* W2, const float* We,
                                              const float* atom_emb, float* dump) {
    int tid = blockIdx.x * 512 + threadIdx.x;
    float s = 0.0f;
#pragma unroll
    for (int p = 0; p < 5; p++) {
        int g = tid + p * 131072;
        const float4* src = nullptr;
        int off = 0;
        if (g < 98304)        { src = (const float4*)Wq;  off = g; }
        else if (g < 294912)  { src = (const float4*)Wkv; off = g - 98304; }
        else if (g < 393216)  { src = (const float4*)Wo;  off = g - 294912; }
        else if (g < 491520)  { src = (const float4*)W1;  off = g - 393216; }
        else if (g < 589824)  { src = (const float4*)W2;  off = g - 491520; }
        else if (g < 592128)  { src = (const float4*)We;  off = g - 589824; }
        else if (g < 595303)  { src = (const float4*)atom_emb; off = g - 592128; }
        if (src) { float4 v = src[off]; s += v.x + v.y + v.z + v.w; }
    }
    if (s == 1.602176634e+30f) dump[0] = s;
}

// Build nodes + LN1(layer 0) -> xn. One block per node, 128 threads.
__global__ __launch_bounds__(128) void k_pre(const int* indices, const float* noise,
                                             const float* atom_emb,
                                             const float* ln1_g, const float* ln1_b,
                                             float* nodes, float* xn) {
    int bn = blockIdx.x;
    int d  = threadIdx.x;
    __shared__ float sb[2];
    int idx = indices[bn];
    float nd = (d < NF) ? atom_emb[idx * NF + d] : noise[0];
    nodes[bn * DIMM + d] = nd;
    float v = nd;
#pragma unroll
    for (int off = 32; off > 0; off >>= 1) v += __shfl_xor(v, off, 64);
    if ((d & 63) == 0) sb[d >> 6] = v;
    __syncthreads();
    float m = (sb[0] + sb[1]) * (1.0f / 128.0f);
    __syncthreads();
    float df = nd - m;
    v = df * df;
#pragma unroll
    for (int off = 32; off > 0; off >>= 1) v += __shfl_xor(v, off, 64);
    if ((d & 63) == 0) sb[d >> 6] = v;
    __syncthreads();
    float var = (sb[0] + sb[1]) * (1.0f / 128.0f);
    xn[bn * DIMM + d] = df * rsqrtf(var + 1e-5f) * ln1_g[d] + ln1_b[d];
}

// QKV GEMM: C[256 x 1536] = xn[256 x 128] @ [Wq|Wkv]. Grid 256 = 16 node-tiles
// x 16 col-tiles (96 cols each). Thread: n = t>>5 (node in tile), s = t&31
// (col-quad slot, 24 active).
__global__ __launch_bounds__(512, 2) void k_qkv(int layer, const float* xn,
                                                const float* Wq, const float* bq,
                                                const float* Wkv, const float* bkv,
                                                float* qb, float* kb, float* vb) {
    int bx = blockIdx.x;
    int nt = bx & 15, ct = bx >> 4;
    int t = threadIdx.x;
    __shared__ float s_x[2048];   // 16 nodes x 128
    ((float4*)s_x)[t] = ((const float4*)(xn + nt * 2048))[t];
    __syncthreads();

    int s = t & 31, n = t >> 5;
    if (s >= 24) return;
    int cqg = ct * 24 + s;      // global col-quad 0..383
    int co  = cqg * 4;          // col 0..1532
    const float4* s_x4 = (const float4*)s_x;

    const float4* Wp;
    int rowQ, cqL;
    float4 acc;
    if (co < 512) {
        Wp = (const float4*)(Wq + (size_t)layer * DIMM * INNER);
        rowQ = 128; cqL = cqg;
        acc = ((const float4*)(bq + (size_t)layer * INNER))[cqg];
    } else {
        Wp = (const float4*)(Wkv + (size_t)layer * DIMM * 2 * INNER);
        rowQ = 256; cqL = cqg - 128;
        acc = ((const float4*)(bkv + (size_t)layer * 2 * INNER))[cqg - 128];
    }
#pragma unroll
    for (int base = 0; base < 128; base += 8) {
        float4 w[8];
#pragma unroll
        for (int p = 0; p < 8; p++) w[p] = Wp[(base + p) * rowQ + cqL];
        float4 x0 = s_x4[n * 32 + (base >> 2)];
        float4 x1 = s_x4[n * 32 + (base >> 2) + 1];
        fma4(acc, x0.x, w[0]); fma4(acc, x0.y, w[1]); fma4(acc, x0.z, w[2]); fma4(acc, x0.w, w[3]);
        fma4(acc, x1.x, w[4]); fma4(acc, x1.y, w[5]); fma4(acc, x1.z, w[6]); fma4(acc, x1.w, w[7]);
    }
    int node = nt * 16 + n;
    if (co < 512)        *((float4*)(qb + (size_t)node * INNER + co)) = acc;
    else if (co < 1024)  *((float4*)(kb + (size_t)node * INNER + co - 512)) = acc;
    else                 *((float4*)(vb + (size_t)node * INNER + co - 1024)) = acc;
}

// Attention: one block per (b,i). 512 thr = 4 j-groups x 128 (head-dim quads).
// Softmax without max-tracking (|sim| small). Writes ao.
__global__ __launch_bounds__(512, 2) void k_attn(int layer, const float* coords,
                                                 const int* bonds,
                                                 const float* We, const float* be,
                                                 const float* qb, const float* kb,
                                                 const float* vb, float* ao) {
    int bn = blockIdx.x;
    int b = bn >> 7, i = bn & 127;
    int t = threadIdx.x;
    int jg = t >> 7, c = t & 127, h = c >> 4;

    __shared__ float scoord[3 * NN];
    __shared__ float sedge[3 * NN];
    __shared__ int   sadj[NN];
    __shared__ float s_o[4 * INNER];
    __shared__ float s_l[4 * HEADS];

    const float4* qR  = (const float4*)(qb + (size_t)bn * INNER);
    const float4* WeR = (const float4*)(We + (size_t)layer * 3 * INNER);
    float4 qv  = qR[c];
    float4 we0 = WeR[c], we1 = WeR[128 + c], we2 = WeR[256 + c];
    float4 bev = ((const float4*)(be + (size_t)layer * INNER))[c];

    if (t < 3 * NN) scoord[t] = coords[b * 3 * NN + t];
    if (t < NN) sadj[t] = 0;
    __syncthreads();
    if (t < EE) {
        int e0 = bonds[2 * t], e1 = bonds[2 * t + 1];
        if (e0 == i) sadj[e1] = 1;
        if (e1 == i) sadj[e0] = 1;
    }
    __syncthreads();
    if (t < NN) {
        int j = t;
        float msk = sadj[j] ? 1.0f : 0.0f;
        sedge[3 * j + 0] = msk * (scoord[3 * i + 0] - scoord[3 * j + 0]);
        sedge[3 * j + 1] = msk * (scoord[3 * i + 1] - scoord[3 * j + 1]);
        sedge[3 * j + 2] = msk * (scoord[3 * i + 2] - scoord[3 * j + 2]);
    }
    __syncthreads();

    const float4* kR = (const float4*)(kb + (size_t)b * NN * INNER);
    const float4* vR = (const float4*)(vb + (size_t)b * NN * INNER);

    float l_run = 0.0f;
    float4 o_run = {0, 0, 0, 0};
    int j0 = jg * 32;
#pragma unroll
    for (int base = 0; base < 32; base += 8) {
        float4 kvv[8], vvv[8];
#pragma unroll
        for (int p = 0; p < 8; p++) {
            int j = j0 + base + p;
            kvv[p] = kR[j * 128 + c];
            vvv[p] = vR[j * 128 + c];
        }
#pragma unroll
        for (int p = 0; p < 8; p++) {
            int j = j0 + base + p;
            float ex = sedge[3 * j], ey = sedge[3 * j + 1], ez = sedge[3 * j + 2];
            float4 e;
            e.x = bev.x + ex * we0.x + ey * we1.x + ez * we2.x;
            e.y = bev.y + ex * we0.y + ey * we1.y + ez * we2.y;
            e.z = bev.z + ex * we0.z + ey * we1.z + ez * we2.z;
            e.w = bev.w + ex * we0.w + ey * we1.w + ez * we2.w;
            float4 kv = kvv[p];
            float sdot = (qv.x * (kv.x + e.x) + qv.y * (kv.y + e.y))
                       + (qv.z * (kv.z + e.z) + qv.w * (kv.w + e.w));
            sdot += __shfl_xor(sdot, 1, 64);
            sdot += __shfl_xor(sdot, 2, 64);
            sdot += __shfl_xor(sdot, 4, 64);
            sdot += __shfl_xor(sdot, 8, 64);
            float pp = __expf(sdot * 0.125f);
            float4 vv = vvv[p];
            l_run += pp;
            o_run.x += pp * (vv.x + e.x);
            o_run.y += pp * (vv.y + e.y);
            o_run.z += pp * (vv.z + e.z);
            o_run.w += pp * (vv.w + e.w);
        }
    }
    ((float4*)(s_o + jg * INNER))[c] = o_run;
    if ((c & 15) == 0) s_l[jg * HEADS + h] = l_run;
    __syncthreads();
    if (jg == 0) {
        float4 o = o_run;
        float l = l_run;
#pragma unroll
        for (int g = 1; g < 4; g++) {
            float4 og = ((float4*)(s_o + g * INNER))[c];
            o.x += og.x; o.y += og.y; o.z += og.z; o.w += og.w;
            l += s_l[g * HEADS + h];
        }
        float inv = 1.0f / l;
        float4 rr; rr.x = o.x * inv; rr.y = o.y * inv; rr.z = o.z * inv; rr.w = o.w * inv;
        ((float4*)(ao + (size_t)bn * INNER))[c] = rr;
    }
}

// Wo GEMM + gate1 + LN2 for 2 nodes/block. Grid 128. GEMM: thread (kg=t>>6,
// r=(t>>5)&1, cq=t&31), K=512 split 8x64.
__global__ __launch_bounds__(512, 2) void k_wo_row(int layer, const float* ao,
                                                   const float* Wo, const float* bo,
                                                   const float* Wg1,
                                                   const float* ln2_g, const float* ln2_b,
                                                   const float* nodes,
                                                   float* xn2, float* n1g) {
    int nb = blockIdx.x;
    int t  = threadIdx.x;
    __shared__ float s_a[1024];     // 2 nodes x 512
    __shared__ float s_part[2048];  // [8 kg][2 r][128 c]
    __shared__ float s_red[8];

    if (t < 256) ((float4*)s_a)[t] = ((const float4*)(ao + (size_t)nb * 1024))[t];
    __syncthreads();

    {
        int kg = t >> 6, r = (t >> 5) & 1, cq = t & 31;
        int k0 = kg * 64;
        const float4* WoR = (const float4*)(Wo + (size_t)layer * INNER * DIMM);
        const float4* s_a4 = (const float4*)s_a;
        float4 acc = {0, 0, 0, 0};
#pragma unroll
        for (int base = 0; base < 64; base += 8) {
            float4 w[8];
#pragma unroll
            for (int p = 0; p < 8; p++) w[p] = WoR[(k0 + base + p) * 32 + cq];
            float4 x0 = s_a4[r * 128 + ((k0 + base) >> 2)];
            float4 x1 = s_a4[r * 128 + ((k0 + base) >> 2) + 1];
            fma4(acc, x0.x, w[0]); fma4(acc, x0.y, w[1]); fma4(acc, x0.z, w[2]); fma4(acc, x0.w, w[3]);
            fma4(acc, x1.x, w[4]); fma4(acc, x1.y, w[5]); fma4(acc, x1.z, w[6]); fma4(acc, x1.w, w[7]);
        }
        ((float4*)(s_part + (kg * 2 + r) * 128))[cq] = acc;
    }
    __syncthreads();

    bool own = (t < 256);
    int r2 = (t >> 7) & 1, d = t & 127;
    int node = nb * 2 + r2;
    float x = 0.0f, res = 0.0f;
    if (own) {
        x = bo[layer * DIMM + d];
#pragma unroll
        for (int kg = 0; kg < 8; kg++) x += s_part[(kg * 2 + r2) * 128 + d];
        res = nodes[node * DIMM + d];
    }
    const float* Wg1_l = Wg1 + layer * 3 * DIMM;
    float texpr = own ? (x * Wg1_l[d] + res * Wg1_l[DIMM + d] + (x - res) * Wg1_l[2 * DIMM + d]) : 0.0f;
    float g1 = group_reduce_128(texpr, s_red);
    g1 = 1.0f / (1.0f + __expf(-g1));
    float n1 = x * g1 + res * (1.0f - g1);

    float m   = group_reduce_128(own ? n1 : 0.0f, s_red) * (1.0f / 128.0f);
    float df  = n1 - m;
    float var = group_reduce_128(own ? df * df : 0.0f, s_red) * (1.0f / 128.0f);
    if (own) {
        float xnv = df * rsqrtf(var + 1e-5f) * ln2_g[layer * DIMM + d] + ln2_b[layer * DIMM + d];
        xn2[node * DIMM + d] = xnv;
        n1g[node * DIMM + d] = n1;
    }
}

// FF1 GEMM + gelu: C[256 x 512] = xn2 @ W1. Grid 64 = 16 node-tiles x 4
// col-tiles (128 cols). Thread (n=t>>5, cq=t&31).
__global__ __launch_bounds__(512, 2) void k_ff1(int layer, const float* xn2,
                                                const float* W1, const float* b1,
                                                float* h) {
    int bx = blockIdx.x;
    int nt = bx >> 2, ct = bx & 3;
    int t = threadIdx.x;
    __shared__ float s_x[2048];
    ((float4*)s_x)[t] = ((const float4*)(xn2 + nt * 2048))[t];
    __syncthreads();

    int n = t >> 5, cq = t & 31;
    const float4* W1R = (const float4*)(W1 + (size_t)layer * DIMM * 4 * DIMM);
    const float4* s_x4 = (const float4*)s_x;
    int cqg = ct * 32 + cq;
    float4 acc = ((const float4*)(b1 + (size_t)layer * 4 * DIMM))[cqg];
#pragma unroll
    for (int base = 0; base < 128; base += 8) {
        float4 w[8];
#pragma unroll
        for (int p = 0; p < 8; p++) w[p] = W1R[(base + p) * 128 + cqg];
        float4 x0 = s_x4[n * 32 + (base >> 2)];
        float4 x1 = s_x4[n * 32 + (base >> 2) + 1];
        fma4(acc, x0.x, w[0]); fma4(acc, x0.y, w[1]); fma4(acc, x0.z, w[2]); fma4(acc, x0.w, w[3]);
        fma4(acc, x1.x, w[4]); fma4(acc, x1.y, w[5]); fma4(acc, x1.z, w[6]); fma4(acc, x1.w, w[7]);
    }
    acc.x = 0.5f * acc.x * (1.0f + erff(acc.x * 0.70710678f));
    acc.y = 0.5f * acc.y * (1.0f + erff(acc.y * 0.70710678f));
    acc.z = 0.5f * acc.z * (1.0f + erff(acc.z * 0.70710678f));
    acc.w = 0.5f * acc.w * (1.0f + erff(acc.w * 0.70710678f));
    int node = nt * 16 + n;
    *((float4*)(h + (size_t)node * INNER + cqg * 4)) = acc;
}

// FF2 GEMM + gate2 + next-layer LN1 for 2 nodes/block. Grid 128.
__global__ __launch_bounds__(512, 2) void k_ff2_row(int layer, const float* h,
                                                    const float* W2, const float* b2,
                                                    const float* Wg2,
                                                    const float* ln1_g, const float* ln1_b,
                                                    const float* n1g,
                                                    float* nodes, float* xn) {
    int nb = blockIdx.x;
    int t  = threadIdx.x;
    __shared__ float s_h[1024];
    __shared__ float s_part[2048];
    __shared__ float s_red[8];

    if (t < 256) ((float4*)s_h)[t] = ((const float4*)(h + (size_t)nb * 1024))[t];
    __syncthreads();

    {
        int kg = t >> 6, r = (t >> 5) & 1, cq = t & 31;
        int k0 = kg * 64;
        const float4* W2R = (const float4*)(W2 + (size_t)layer * 4 * DIMM * DIMM);
        const float4* s_h4 = (const float4*)s_h;
        float4 acc = {0, 0, 0, 0};
#pragma unroll
        for (int base = 0; base < 64; base += 8) {
            float4 w[8];
#pragma unroll
            for (int p = 0; p < 8; p++) w[p] = W2R[(k0 + base + p) * 32 + cq];
            float4 x0 = s_h4[r * 128 + ((k0 + base) >> 2)];
            float4 x1 = s_h4[r * 128 + ((k0 + base) >> 2) + 1];
            fma4(acc, x0.x, w[0]); fma4(acc, x0.y, w[1]); fma4(acc, x0.z, w[2]); fma4(acc, x0.w, w[3]);
            fma4(acc, x1.x, w[4]); fma4(acc, x1.y, w[5]); fma4(acc, x1.z, w[6]); fma4(acc, x1.w, w[7]);
        }
        ((float4*)(s_part + (kg * 2 + r) * 128))[cq] = acc;
    }
    __syncthreads();

    bool own = (t < 256);
    int r2 = (t >> 7) & 1, d = t & 127;
    int node = nb * 2 + r2;
    float y = 0.0f, n1 = 0.0f;
    if (own) {
        y = b2[layer * DIMM + d];
#pragma unroll
        for (int kg = 0; kg < 8; kg++) y += s_part[(kg * 2 + r2) * 128 + d];
        n1 = n1g[node * DIMM + d];
    }
    const float* Wg2_l = Wg2 + layer * 3 * DIMM;
    float texpr = own ? (y * Wg2_l[d] + n1 * Wg2_l[DIMM + d] + (y - n1) * Wg2_l[2 * DIMM + d]) : 0.0f;
    float g2 = group_reduce_128(texpr, s_red);
    g2 = 1.0f / (1.0f + __expf(-g2));
    float n2 = y * g2 + n1 * (1.0f - g2);
    if (own) nodes[node * DIMM + d] = n2;

    if (layer < DEPTH - 1) {
        float m   = group_reduce_128(own ? n2 : 0.0f, s_red) * (1.0f / 128.0f);
        float df  = n2 - m;
        float var = group_reduce_128(own ? df * df : 0.0f, s_red) * (1.0f / 128.0f);
        if (own) {
            int nl = layer + 1;
            xn[node * DIMM + d] = df * rsqrtf(var + 1e-5f) * ln1_g[nl * DIMM + d]
                                + ln1_b[nl * DIMM + d];
        }
    }
}

// Final: sum over nodes of (nodes @ Wlin + blin) -> scalar.
__global__ __launch_bounds__(256) void k_final(const float* nodes, const float* Wlin,
                                               const float* blin, float* out) {
    int t = threadIdx.x;
    __shared__ float s_w[DIMM];
    if (t < DIMM) s_w[t] = Wlin[t];
    __syncthreads();
    float s = blin[0];
    const float4* nr = (const float4*)(nodes + t * DIMM);
#pragma unroll 8
    for (int q = 0; q < 32; q++) {
        float4 n = nr[q];
        s += n.x * s_w[4 * q] + n.y * s_w[4 * q + 1] + n.z * s_w[4 * q + 2] + n.w * s_w[4 * q + 3];
    }
#pragma unroll
    for (int off = 32; off > 0; off >>= 1) s += __shfl_xor(s, off, 64);
    __shared__ float sb[4];
    int wave = t >> 6, lane = t & 63;
    if (lane == 0) sb[wave] = s;
    __syncthreads();
    if (t == 0) out[0] = sb[0] + sb[1] + sb[2] + sb[3];
}

extern "C" void kernel_launch(void* const* d_in, const int* in_sizes, int n_in,
                              void* d_out, int out_size, void* d_ws, size_t ws_size,
                              hipStream_t stream) {
    const int*   indices = (const int*)d_in[0];
    const float* coords  = (const float*)d_in[1];
    const int*   bonds   = (const int*)d_in[2];
    const float* noise   = (const float*)d_in[3];
    const float* atom_emb= (const float*)d_in[4];
    const float* ln1_g   = (const float*)d_in[5];
    const float* ln1_b   = (const float*)d_in[6];
    const float* Wq      = (const float*)d_in[7];
    const float* bq      = (const float*)d_in[8];
    const float* Wkv     = (const float*)d_in[9];
    const float* bkv     = (const float*)d_in[10];
    const float* We      = (const float*)d_in[11];
    const float* be      = (const float*)d_in[12];
    const float* Wo      = (const float*)d_in[13];
    const float* bo      = (const float*)d_in[14];
    const float* Wg1     = (const float*)d_in[15];
    const float* ln2_g   = (const float*)d_in[16];
    const float* ln2_b   = (const float*)d_in[17];
    const float* W1      = (const float*)d_in[18];
    const float* b1      = (const float*)d_in[19];
    const float* W2      = (const float*)d_in[20];
    const float* b2      = (const float*)d_in[21];
    const float* Wg2     = (const float*)d_in[22];
    const float* Wlin    = (const float*)d_in[23];
    const float* blin    = (const float*)d_in[24];

    float* ws    = (float*)d_ws;
    float* nodes = ws;                        // 32768
    float* xn    = nodes + NNODE * DIMM;      // 32768
    float* xn2   = xn    + NNODE * DIMM;      // 32768
    float* n1g   = xn2   + NNODE * DIMM;      // 32768
    float* qb    = n1g   + NNODE * DIMM;      // 131072
    float* kb    = qb    + NNODE * INNER;
    float* vb    = kb    + NNODE * INNER;
    float* ao    = vb    + NNODE * INNER;
    float* h     = ao    + NNODE * INNER;

    k_warm<<<256, 512, 0, stream>>>(Wq, Wkv, Wo, W1, W2, We, atom_emb, nodes);
    k_pre<<<NNODE, 128, 0, stream>>>(indices, noise, atom_emb, ln1_g, ln1_b, nodes, xn);
    for (int l = 0; l < DEPTH; l++) {
        k_qkv<<<256, 512, 0, stream>>>(l, xn, Wq, bq, Wkv, bkv, qb, kb, vb);
        k_attn<<<NNODE, 512, 0, stream>>>(l, coords, bonds, We, be, qb, kb, vb, ao);
        k_wo_row<<<128, 512, 0, stream>>>(l, ao, Wo, bo, Wg1, ln2_g, ln2_b,
                                          nodes, xn2, n1g);
        k_ff1<<<64, 512, 0, stream>>>(l, xn2, W1, b1, h);
        k_ff2_row<<<128, 512, 0, stream>>>(l, h, W2, b2, Wg2, ln1_g, ln1_b,
                                           n1g, nodes, xn);
    }
    k_final<<<1, 256, 0, stream>>>(nodes, Wlin, blin, (float*)d_out);
}

// Round 10
// 377.483 us; speedup vs baseline: 2.1611x; 2.1611x over previous
//
#include <hip/hip_runtime.h>
#include <math.h>

#define DEPTH 6
#define HEADS 8
#define BB    2
#define NN    128
#define EE    160
#define NF    127
#define DIMM  128
#define INNER 512

#define KV_SLAB (BB * NN * INNER)   // floats per k/v slab

__device__ __forceinline__ void fma4(float4& acc, float a, const float4 w) {
    acc.x += a * w.x; acc.y += a * w.y; acc.z += a * w.z; acc.w += a * w.w;
}

// async global->LDS DMA, 16B per lane. LDS dest = wave-uniform base + lane*16.
__device__ __forceinline__ void gload16(const float* g, float* l) {
    __builtin_amdgcn_global_load_lds((const __attribute__((address_space(1))) void*)g,
                                     (__attribute__((address_space(3))) void*)l,
                                     16, 0, 0);
}

// Stage one 32 KB chunk (8192 floats) linearly into LDS. 512 threads x 4 rounds.
// Round r, thread t copies float4 index r*512+t; LDS ends up a linear mirror.
__device__ __forceinline__ void stage32k(const float* g, float* lds) {
    int t = threadIdx.x;
    const float* gt = g + t * 4;
    float* lb = lds + (t >> 6) * 256;   // wave-uniform base (floats)
#pragma unroll
    for (int r = 0; r < 4; r++) gload16(gt + r * 2048, lb + r * 2048);
}

// 512-thread (8-wave) block sum; result broadcast.
__device__ __forceinline__ float block_reduce_sum_8w(float val, float* sbuf) {
#pragma unroll
    for (int off = 32; off > 0; off >>= 1) val += __shfl_xor(val, off, 64);
    int wave = threadIdx.x >> 6;
    if ((threadIdx.x & 63) == 0) sbuf[wave] = val;
    __syncthreads();
    float r = sbuf[0] + sbuf[1] + sbuf[2] + sbuf[3] + sbuf[4] + sbuf[5] + sbuf[6] + sbuf[7];
    __syncthreads();
    return r;
}

// QKV projection from s_xn (LN1 output) using LDS-staged weights.
// s_part: >=4096 floats. st: 16384 floats (2x8192 dbuf).
__device__ void qkv_staged(int t, int bn, int layer,
                           const float* Wq, const float* bq,
                           const float* Wkv, const float* bkv,
                           float* qout, float* kout, float* vout,
                           const float* s_xn, float* s_part, float* st) {
    float* buf0 = st;
    float* buf1 = st + 8192;
    int c7 = t & 127, kg4 = t >> 7;

    // ---- Wq: [128 x 512], 8 chunks x 16 rows
    const float* WqL = Wq + (size_t)layer * DIMM * INNER;
    float4 aq = {0, 0, 0, 0};
    stage32k(WqL, buf0);
    for (int c = 0; c < 8; c++) {
        __syncthreads();   // drains DMA(c), publishes chunk c
        if (c < 7) stage32k(WqL + (c + 1) * 8192, (c & 1) ? buf0 : buf1);
        const float4* w4 = (const float4*)((c & 1) ? buf1 : buf0);
        int rb = kg4 * 4;
#pragma unroll
        for (int rr = 0; rr < 4; rr++)
            fma4(aq, s_xn[c * 16 + rb + rr], w4[(rb + rr) * 128 + c7]);
    }
    ((float4*)(s_part + kg4 * 512))[c7] = aq;
    __syncthreads();
    {
        float q = bq[layer * INNER + t];
#pragma unroll
        for (int g = 0; g < 4; g++) q += s_part[g * 512 + t];
        qout[(size_t)bn * INNER + t] = q;
    }

    // ---- Wkv: [128 x 1024], 16 chunks x 8 rows
    const float* WkvL = Wkv + (size_t)layer * DIMM * 2 * INNER;
    float4 ak = {0, 0, 0, 0}, av = {0, 0, 0, 0};
    stage32k(WkvL, buf0);
    for (int c = 0; c < 16; c++) {
        __syncthreads();
        if (c < 15) stage32k(WkvL + (c + 1) * 8192, (c & 1) ? buf0 : buf1);
        const float4* w4 = (const float4*)((c & 1) ? buf1 : buf0);
        int rb = kg4 * 2;
#pragma unroll
        for (int rr = 0; rr < 2; rr++) {
            float a = s_xn[c * 8 + rb + rr];
            fma4(ak, a, w4[(rb + rr) * 256 + c7]);
            fma4(av, a, w4[(rb + rr) * 256 + 128 + c7]);
        }
    }
    ((float4*)(s_part + kg4 * 512))[c7] = ak;
    ((float4*)(s_part + 2048 + kg4 * 512))[c7] = av;
    __syncthreads();
    {
        float k = bkv[layer * 2 * INNER + t];
        float v = bkv[layer * 2 * INNER + INNER + t];
#pragma unroll
        for (int g = 0; g < 4; g++) {
            k += s_part[g * 512 + t];
            v += s_part[2048 + g * 512 + t];
        }
        kout[(size_t)bn * INNER + t] = k;
        vout[(size_t)bn * INNER + t] = v;
    }
    __syncthreads();
}

// ---------- kernels ----------

// Warm weights into L3 at HBM BW (poison between replays evicts everything).
__global__ __launch_bounds__(512) void k_warm(const float* Wq, const float* Wkv,
                                              const float* Wo, const float* W1,
                                              const float* W2, const float* We,
                                              const float* atom_emb, float* dump) {
    int tid = blockIdx.x * 512 + threadIdx.x;
    float s = 0.0f;
#pragma unroll
    for (int p = 0; p < 5; p++) {
        int g = tid + p * 131072;
        const float4* src = nullptr;
        int off = 0;
        if (g < 98304)        { src = (const float4*)Wq;  off = g; }
        else if (g < 294912)  { src = (const float4*)Wkv; off = g - 98304; }
        else if (g < 393216)  { src = (const float4*)Wo;  off = g - 294912; }
        else if (g < 491520)  { src = (const float4*)W1;  off = g - 393216; }
        else if (g < 589824)  { src = (const float4*)W2;  off = g - 491520; }
        else if (g < 592128)  { src = (const float4*)We;  off = g - 589824; }
        else if (g < 595303)  { src = (const float4*)atom_emb; off = g - 592128; }
        if (src) { float4 v = src[off]; s += v.x + v.y + v.z + v.w; }
    }
    if (s == 1.602176634e+30f) dump[0] = s;
}

// Build nodes + LN1 + staged QKV for layer 0.
__global__ __launch_bounds__(512, 2) void k_pre(const int* indices, const float* noise,
                                                const float* atom_emb,
                                                const float* ln1_g, const float* ln1_b,
                                                const float* Wq, const float* bq,
                                                const float* Wkv, const float* bkv,
                                                float* nodes, float* qb, float* kb, float* vb) {
    int bn = blockIdx.x;
    int t  = threadIdx.x;
    int d  = t & 127;
    bool own = (t < 128);
    __shared__ float s_xn[128];
    __shared__ float s_red[8];
    __shared__ float s_part[4096];
    __shared__ float s_stage[16384];

    float nd = 0.0f;
    if (own) {
        int idx = indices[bn];
        nd = (d < NF) ? atom_emb[idx * NF + d] : noise[0];
        nodes[bn * DIMM + d] = nd;
    }
    float m   = block_reduce_sum_8w(own ? nd : 0.0f, s_red) * (1.0f / 128.0f);
    float df  = nd - m;
    float var = block_reduce_sum_8w(own ? df * df : 0.0f, s_red) * (1.0f / 128.0f);
    if (own) s_xn[d] = df * rsqrtf(var + 1e-5f) * ln1_g[d] + ln1_b[d];
    __syncthreads();

    qkv_staged(t, bn, 0, Wq, bq, Wkv, bkv, qb, kb, vb, s_xn, s_part, s_stage);
}

// Fused per-layer kernel: attention + post pipeline (LDS-staged weights) +
// next-layer staged QKV. k/v double-buffered by layer parity.
__global__ __launch_bounds__(512, 2) void k_layer(int layer,
        const float* coords, const int* bonds,
        const float* We, const float* be,
        float* qb, const float* kin, const float* vin,
        float* kout, float* vout,
        const float* Wo, const float* bo, const float* Wg1,
        const float* ln2_g, const float* ln2_b,
        const float* W1, const float* b1,
        const float* W2, const float* b2,
        const float* Wg2,
        const float* ln1_g, const float* ln1_b,
        const float* Wq, const float* bq,
        const float* Wkv, const float* bkv,
        float* nodes) {
    int bn = blockIdx.x;
    int b = bn >> 7, i = bn & 127;
    int t = threadIdx.x;
    int d = t & 127;
    bool own = (t < 128);

    __shared__ float scoord[3 * NN];
    __shared__ float sedge[3 * NN];
    __shared__ int   sadj[NN];
    __shared__ float s_o[4 * INNER];
    __shared__ float s_l[4 * HEADS];
    __shared__ float s_ao[INNER];
    __shared__ float s_h[INNER];
    __shared__ float s_xn[128];
    __shared__ float s_red[8];
    __shared__ float s_part[4096];
    __shared__ float s_stage[16384];
    float* buf0 = s_stage;
    float* buf1 = s_stage + 8192;

    // ---------- Phase A: attention ----------
    int jg = t >> 7;     // 0..3, each handles 32 j's
    int c  = t & 127;    // head-dim quad; head h = c>>4
    int h  = c >> 4;

    const float4* qR  = (const float4*)(qb + (size_t)bn * INNER);
    const float4* WeR = (const float4*)(We + (size_t)layer * 3 * INNER);
    float4 qv  = qR[c];
    float4 we0 = WeR[c], we1 = WeR[128 + c], we2 = WeR[256 + c];
    float4 bev = ((const float4*)(be + (size_t)layer * INNER))[c];
    float res = own ? nodes[bn * DIMM + d] : 0.0f;

    if (t < 3 * NN) scoord[t] = coords[b * 3 * NN + t];
    if (t < NN) sadj[t] = 0;
    __syncthreads();
    if (t < EE) {
        int e0 = bonds[2 * t], e1 = bonds[2 * t + 1];
        if (e0 == i) sadj[e1] = 1;
        if (e1 == i) sadj[e0] = 1;
    }
    __syncthreads();
    if (t < NN) {
        int j = t;
        float msk = sadj[j] ? 1.0f : 0.0f;
        sedge[3 * j + 0] = msk * (scoord[3 * i + 0] - scoord[3 * j + 0]);
        sedge[3 * j + 1] = msk * (scoord[3 * i + 1] - scoord[3 * j + 1]);
        sedge[3 * j + 2] = msk * (scoord[3 * i + 2] - scoord[3 * j + 2]);
    }
    __syncthreads();

    const float4* kR = (const float4*)(kin + (size_t)b * NN * INNER);
    const float4* vR = (const float4*)(vin + (size_t)b * NN * INNER);

    float l_run = 0.0f;
    float4 o_run = {0, 0, 0, 0};
    int j0 = jg * 32;
#pragma unroll
    for (int base = 0; base < 32; base += 8) {
        float4 kvv[8], vvv[8];
#pragma unroll
        for (int p = 0; p < 8; p++) {
            int j = j0 + base + p;
            kvv[p] = kR[j * 128 + c];
            vvv[p] = vR[j * 128 + c];
        }
#pragma unroll
        for (int p = 0; p < 8; p++) {
            int j = j0 + base + p;
            float ex = sedge[3 * j], ey = sedge[3 * j + 1], ez = sedge[3 * j + 2];
            float4 e;
            e.x = bev.x + ex * we0.x + ey * we1.x + ez * we2.x;
            e.y = bev.y + ex * we0.y + ey * we1.y + ez * we2.y;
            e.z = bev.z + ex * we0.z + ey * we1.z + ez * we2.z;
            e.w = bev.w + ex * we0.w + ey * we1.w + ez * we2.w;
            float4 kv = kvv[p];
            float s = (qv.x * (kv.x + e.x) + qv.y * (kv.y + e.y))
                    + (qv.z * (kv.z + e.z) + qv.w * (kv.w + e.w));
            s += __shfl_xor(s, 1, 64);
            s += __shfl_xor(s, 2, 64);
            s += __shfl_xor(s, 4, 64);
            s += __shfl_xor(s, 8, 64);
            float pp = __expf(s * 0.125f);
            float4 vv = vvv[p];
            l_run += pp;
            o_run.x += pp * (vv.x + e.x);
            o_run.y += pp * (vv.y + e.y);
            o_run.z += pp * (vv.z + e.z);
            o_run.w += pp * (vv.w + e.w);
        }
    }
    ((float4*)(s_o + jg * INNER))[c] = o_run;
    if ((c & 15) == 0) s_l[jg * HEADS + h] = l_run;
    __syncthreads();
    if (jg == 0) {
        float4 o = o_run;
        float l = l_run;
#pragma unroll
        for (int g = 1; g < 4; g++) {
            float4 og = ((float4*)(s_o + g * INNER))[c];
            o.x += og.x; o.y += og.y; o.z += og.z; o.w += og.w;
            l += s_l[g * HEADS + h];
        }
        float inv = 1.0f / l;
        float4 rr; rr.x = o.x * inv; rr.y = o.y * inv; rr.z = o.z * inv; rr.w = o.w * inv;
        ((float4*)s_ao)[c] = rr;
    }
    __syncthreads();

    // ---------- Phase B: post pipeline, LDS-staged weights ----------
    int c5 = t & 31, kg16 = t >> 5;

    // Wo: [512 x 128], 8 chunks x 64 rows
    {
        const float* WoL = Wo + (size_t)layer * INNER * DIMM;
        float4 acw = {0, 0, 0, 0};
        stage32k(WoL, buf0);
        for (int cc = 0; cc < 8; cc++) {
            __syncthreads();
            if (cc < 7) stage32k(WoL + (cc + 1) * 8192, (cc & 1) ? buf0 : buf1);
            const float4* w4 = (const float4*)((cc & 1) ? buf1 : buf0);
            int rb = kg16 * 4;
#pragma unroll
            for (int rr = 0; rr < 4; rr++)
                fma4(acw, s_ao[cc * 64 + rb + rr], w4[(rb + rr) * 32 + c5]);
        }
        ((float4*)(s_part + kg16 * 128))[c5] = acw;
    }
    __syncthreads();
    float x = 0.0f;
    if (own) {
        x = bo[layer * DIMM + d];
#pragma unroll
        for (int g = 0; g < 16; g++) x += s_part[g * 128 + d];
    }

    // gated residual 1
    const float* Wg1_l = Wg1 + layer * 3 * DIMM;
    float texpr = own ? (x * Wg1_l[d] + res * Wg1_l[DIMM + d] + (x - res) * Wg1_l[2 * DIMM + d]) : 0.0f;
    float g1 = block_reduce_sum_8w(texpr, s_red);
    g1 = 1.0f / (1.0f + __expf(-g1));
    float n1 = x * g1 + res * (1.0f - g1);

    // LN2
    float m   = block_reduce_sum_8w(own ? n1 : 0.0f, s_red) * (1.0f / 128.0f);
    float df  = n1 - m;
    float var = block_reduce_sum_8w(own ? df * df : 0.0f, s_red) * (1.0f / 128.0f);
    float xn  = df * rsqrtf(var + 1e-5f) * ln2_g[layer * DIMM + d] + ln2_b[layer * DIMM + d];
    if (own) s_xn[d] = xn;
    __syncthreads();

    // FF1: W1 [128 x 512], 8 chunks x 16 rows, + exact gelu
    int c7 = t & 127, kg4 = t >> 7;
    {
        const float* W1L = W1 + (size_t)layer * DIMM * 4 * DIMM;
        float4 ac1 = {0, 0, 0, 0};
        stage32k(W1L, buf0);
        for (int cc = 0; cc < 8; cc++) {
            __syncthreads();
            if (cc < 7) stage32k(W1L + (cc + 1) * 8192, (cc & 1) ? buf0 : buf1);
            const float4* w4 = (const float4*)((cc & 1) ? buf1 : buf0);
            int rb = kg4 * 4;
#pragma unroll
            for (int rr = 0; rr < 4; rr++)
                fma4(ac1, s_xn[cc * 16 + rb + rr], w4[(rb + rr) * 128 + c7]);
        }
        ((float4*)(s_part + kg4 * 512))[c7] = ac1;
    }
    __syncthreads();
    {
        float a = b1[layer * 4 * DIMM + t];
#pragma unroll
        for (int g = 0; g < 4; g++) a += s_part[g * 512 + t];
        a = 0.5f * a * (1.0f + erff(a * 0.70710678f));
        s_h[t] = a;
    }
    __syncthreads();

    // FF2: W2 [512 x 128], 8 chunks x 64 rows
    {
        const float* W2L = W2 + (size_t)layer * 4 * DIMM * DIMM;
        float4 ac2 = {0, 0, 0, 0};
        stage32k(W2L, buf0);
        for (int cc = 0; cc < 8; cc++) {
            __syncthreads();
            if (cc < 7) stage32k(W2L + (cc + 1) * 8192, (cc & 1) ? buf0 : buf1);
            const float4* w4 = (const float4*)((cc & 1) ? buf1 : buf0);
            int rb = kg16 * 4;
#pragma unroll
            for (int rr = 0; rr < 4; rr++)
                fma4(ac2, s_h[cc * 64 + rb + rr], w4[(rb + rr) * 32 + c5]);
        }
        ((float4*)(s_part + kg16 * 128))[c5] = ac2;
    }
    __syncthreads();
    float y = 0.0f;
    if (own) {
        y = b2[layer * DIMM + d];
#pragma unroll
        for (int g = 0; g < 16; g++) y += s_part[g * 128 + d];
    }

    // gated residual 2
    const float* Wg2_l = Wg2 + layer * 3 * DIMM;
    texpr = own ? (y * Wg2_l[d] + n1 * Wg2_l[DIMM + d] + (y - n1) * Wg2_l[2 * DIMM + d]) : 0.0f;
    float g2 = block_reduce_sum_8w(texpr, s_red);
    g2 = 1.0f / (1.0f + __expf(-g2));
    float n2 = y * g2 + n1 * (1.0f - g2);
    if (own) nodes[bn * DIMM + d] = n2;

    if (layer < DEPTH - 1) {
        // LN1 for next layer
        float m1   = block_reduce_sum_8w(own ? n2 : 0.0f, s_red) * (1.0f / 128.0f);
        float df1  = n2 - m1;
        float var1 = block_reduce_sum_8w(own ? df1 * df1 : 0.0f, s_red) * (1.0f / 128.0f);
        if (own) s_xn[d] = df1 * rsqrtf(var1 + 1e-5f) * ln1_g[(layer + 1) * DIMM + d]
                         + ln1_b[(layer + 1) * DIMM + d];
        __syncthreads();
        qkv_staged(t, bn, layer + 1, Wq, bq, Wkv, bkv, qb, kout, vout,
                   s_xn, s_part, s_stage);
    }
}

// Final: sum over nodes of (nodes @ Wlin + blin) -> scalar.
__global__ __launch_bounds__(256) void k_final(const float* nodes, const float* Wlin,
                                               const float* blin, float* out) {
    int t = threadIdx.x;
    __shared__ float s_w[DIMM];
    if (t < DIMM) s_w[t] = Wlin[t];
    __syncthreads();
    float s = blin[0];
    const float4* nr = (const float4*)(nodes + t * DIMM);
#pragma unroll 8
    for (int q = 0; q < 32; q++) {
        float4 n = nr[q];
        s += n.x * s_w[4 * q] + n.y * s_w[4 * q + 1] + n.z * s_w[4 * q + 2] + n.w * s_w[4 * q + 3];
    }
#pragma unroll
    for (int off = 32; off > 0; off >>= 1) s += __shfl_xor(s, off, 64);
    __shared__ float sb[4];
    int wave = t >> 6, lane = t & 63;
    if (lane == 0) sb[wave] = s;
    __syncthreads();
    if (t == 0) out[0] = sb[0] + sb[1] + sb[2] + sb[3];
}

extern "C" void kernel_launch(void* const* d_in, const int* in_sizes, int n_in,
                              void* d_out, int out_size, void* d_ws, size_t ws_size,
                              hipStream_t stream) {
    const int*   indices = (const int*)d_in[0];
    const float* coords  = (const float*)d_in[1];
    const int*   bonds   = (const int*)d_in[2];
    const float* noise   = (const float*)d_in[3];
    const float* atom_emb= (const float*)d_in[4];
    const float* ln1_g   = (const float*)d_in[5];
    const float* ln1_b   = (const float*)d_in[6];
    const float* Wq      = (const float*)d_in[7];
    const float* bq      = (const float*)d_in[8];
    const float* Wkv     = (const float*)d_in[9];
    const float* bkv     = (const float*)d_in[10];
    const float* We      = (const float*)d_in[11];
    const float* be      = (const float*)d_in[12];
    const float* Wo      = (const float*)d_in[13];
    const float* bo      = (const float*)d_in[14];
    const float* Wg1     = (const float*)d_in[15];
    const float* ln2_g   = (const float*)d_in[16];
    const float* ln2_b   = (const float*)d_in[17];
    const float* W1      = (const float*)d_in[18];
    const float* b1      = (const float*)d_in[19];
    const float* W2      = (const float*)d_in[20];
    const float* b2      = (const float*)d_in[21];
    const float* Wg2     = (const float*)d_in[22];
    const float* Wlin    = (const float*)d_in[23];
    const float* blin    = (const float*)d_in[24];

    float* ws    = (float*)d_ws;
    float* nodes = ws;                       // 32768 floats
    float* qb    = nodes + BB * NN * DIMM;   // 131072 floats
    float* kb    = qb + KV_SLAB;             // 2 slabs
    float* vb    = kb + 2 * KV_SLAB;         // 2 slabs

    k_warm<<<256, 512, 0, stream>>>(Wq, Wkv, Wo, W1, W2, We, atom_emb, nodes);
    k_pre<<<BB * NN, 512, 0, stream>>>(indices, noise, atom_emb, ln1_g, ln1_b,
                                       Wq, bq, Wkv, bkv, nodes, qb, kb, vb);
    for (int l = 0; l < DEPTH; l++) {
        const float* kin = kb + (size_t)(l & 1) * KV_SLAB;
        const float* vin = vb + (size_t)(l & 1) * KV_SLAB;
        float* kout = kb + (size_t)((l + 1) & 1) * KV_SLAB;
        float* vout = vb + (size_t)((l + 1) & 1) * KV_SLAB;
        k_layer<<<BB * NN, 512, 0, stream>>>(l, coords, bonds, We, be,
                                             qb, kin, vin, kout, vout,
                                             Wo, bo, Wg1, ln2_g, ln2_b, W1, b1, W2, b2,
                                             Wg2, ln1_g, ln1_b, Wq, bq, Wkv, bkv, nodes);
    }
    k_final<<<1, 256, 0, stream>>>(nodes, Wlin, blin, (float*)d_out);
}

// Round 11
// 316.978 us; speedup vs baseline: 2.5736x; 1.1909x over previous
//
#include <hip/hip_runtime.h>
#include <hip/hip_fp16.h>
#include <math.h>

#define DEPTH 6
#define HEADS 8
#define BB    2
#define NN    128
#define EE    160
#define NF    127
#define DIMM  128
#define INNER 512
#define NNODE (BB * NN)

__device__ __forceinline__ void fma4(float4& acc, float a, const float4 w) {
    acc.x += a * w.x; acc.y += a * w.y; acc.z += a * w.z; acc.w += a * w.w;
}

// acc += a * (4 halves packed in an 8-byte float2)
__device__ __forceinline__ void fma4h(float4& acc, float a, float2 raw) {
    const __half2* hp = (const __half2*)&raw;
    float2 lo = __half22float2(hp[0]);
    float2 hi = __half22float2(hp[1]);
    acc.x += a * lo.x; acc.y += a * lo.y; acc.z += a * hi.x; acc.w += a * hi.y;
}

// async global->LDS DMA, 16B per lane.
__device__ __forceinline__ void gload16(const void* g, void* l) {
    __builtin_amdgcn_global_load_lds((const __attribute__((address_space(1))) void*)g,
                                     (__attribute__((address_space(3))) void*)l,
                                     16, 0, 0);
}

// Stage one 32 KB chunk linearly into LDS (512 threads x 4 DMA each).
__device__ __forceinline__ void stage32kB(const void* g, void* lds) {
    int t = threadIdx.x;
    const char* gt = (const char*)g + t * 16;
    char* lb = (char*)lds + (t >> 6) * 1024;   // wave-uniform base
#pragma unroll
    for (int r = 0; r < 4; r++) gload16(gt + r * 8192, lb + r * 8192);
}

// 512-thread (8-wave) block sum; result broadcast.
__device__ __forceinline__ float block_reduce_sum_8w(float val, float* sbuf) {
#pragma unroll
    for (int off = 32; off > 0; off >>= 1) val += __shfl_xor(val, off, 64);
    int wave = threadIdx.x >> 6;
    if ((threadIdx.x & 63) == 0) sbuf[wave] = val;
    __syncthreads();
    float r = sbuf[0] + sbuf[1] + sbuf[2] + sbuf[3] + sbuf[4] + sbuf[5] + sbuf[6] + sbuf[7];
    __syncthreads();
    return r;
}

// QKV projection from s_xn using fp16 LDS-staged weights. q fp32; k,v fp16.
// st: 2 x 8192 floats (2 x 32 KB). s_part >= 4096 floats.
__device__ void qkv_staged_h(int t, int bn, int layer,
                             const __half* hWq, const float* bq,
                             const __half* hWkv, const float* bkv,
                             float* qout, __half* hkout, __half* hvout,
                             const float* s_xn, float* s_part, float* st) {
    float* buf0 = st;
    float* buf1 = st + 8192;
    int c7 = t & 127, kg4 = t >> 7;

    // Wq fp16: [128 x 512] = 128 KB = 4 chunks x 32 rows. kg4 owns 8 rows/chunk.
    const __half* WqL = hWq + (size_t)layer * DIMM * INNER;
    float4 aq = {0, 0, 0, 0};
    stage32kB(WqL, buf0);
    for (int c = 0; c < 4; c++) {
        __syncthreads();
        if (c < 3) stage32kB(WqL + (c + 1) * 16384, (c & 1) ? buf0 : buf1);
        const float2* w2 = (const float2*)((c & 1) ? buf1 : buf0);
#pragma unroll
        for (int rr = 0; rr < 8; rr++) {
            int row = kg4 * 8 + rr;
            fma4h(aq, s_xn[c * 32 + row], w2[row * 128 + c7]);
        }
    }
    ((float4*)(s_part + kg4 * 512))[c7] = aq;
    __syncthreads();
    {
        float q = bq[layer * INNER + t];
#pragma unroll
        for (int g = 0; g < 4; g++) q += s_part[g * 512 + t];
        qout[(size_t)bn * INNER + t] = q;
    }

    // Wkv fp16: [128 x 1024] = 256 KB = 8 chunks x 16 rows. kg4 owns 4 rows/chunk.
    const __half* WkvL = hWkv + (size_t)layer * DIMM * 2 * INNER;
    float4 ak = {0, 0, 0, 0}, av = {0, 0, 0, 0};
    stage32kB(WkvL, buf0);
    for (int c = 0; c < 8; c++) {
        __syncthreads();
        if (c < 7) stage32kB(WkvL + (c + 1) * 16384, (c & 1) ? buf0 : buf1);
        const float2* w2 = (const float2*)((c & 1) ? buf1 : buf0);
#pragma unroll
        for (int rr = 0; rr < 4; rr++) {
            int row = kg4 * 4 + rr;
            float a = s_xn[c * 16 + row];
            fma4h(ak, a, w2[row * 256 + c7]);
            fma4h(av, a, w2[row * 256 + 128 + c7]);
        }
    }
    ((float4*)(s_part + kg4 * 512))[c7] = ak;
    ((float4*)(s_part + 2048 + kg4 * 512))[c7] = av;
    __syncthreads();
    {
        float k = bkv[layer * 2 * INNER + t];
        float v = bkv[layer * 2 * INNER + INNER + t];
#pragma unroll
        for (int g = 0; g < 4; g++) {
            k += s_part[g * 512 + t];
            v += s_part[2048 + g * 512 + t];
        }
        hkout[(size_t)bn * INNER + t] = __float2half(k);
        hvout[(size_t)bn * INNER + t] = __float2half(v);
    }
    __syncthreads();
}

// ---------- kernels ----------

// Convert all big weights fp32 -> fp16 into ws (also warms L3). Grid 1152 x 512.
__global__ __launch_bounds__(512) void k_cvt(const float* Wq, const float* Wkv,
                                             const float* Wo, const float* W1,
                                             const float* W2,
                                             __half* hWq, __half* hWkv, __half* hWo,
                                             __half* hW1, __half* hW2) {
    int g = blockIdx.x * 512 + threadIdx.x;  // float4 index, 0..589823
    const float4* src;
    __half* dst;
    int off;
    if (g < 98304)       { src = (const float4*)Wq;  dst = hWq;  off = g; }
    else if (g < 294912) { src = (const float4*)Wkv; dst = hWkv; off = g - 98304; }
    else if (g < 393216) { src = (const float4*)Wo;  dst = hWo;  off = g - 294912; }
    else if (g < 491520) { src = (const float4*)W1;  dst = hW1;  off = g - 393216; }
    else                 { src = (const float4*)W2;  dst = hW2;  off = g - 491520; }
    float4 v = src[off];
    __half2* d2 = (__half2*)(dst + (size_t)off * 4);
    d2[0] = __floats2half2_rn(v.x, v.y);
    d2[1] = __floats2half2_rn(v.z, v.w);
}

// Build nodes + LN1 + staged QKV for layer 0.
__global__ __launch_bounds__(512, 2) void k_pre(const int* indices, const float* noise,
                                                const float* atom_emb,
                                                const float* ln1_g, const float* ln1_b,
                                                const __half* hWq, const float* bq,
                                                const __half* hWkv, const float* bkv,
                                                float* nodes, float* qb,
                                                __half* hkb, __half* hvb) {
    int bn = blockIdx.x;
    int t  = threadIdx.x;
    int d  = t & 127;
    bool own = (t < 128);
    __shared__ float s_xn[128];
    __shared__ float s_red[8];
    __shared__ float s_part[4096];
    __shared__ float s_stage[16384];

    float nd = 0.0f;
    if (own) {
        int idx = indices[bn];
        nd = (d < NF) ? atom_emb[idx * NF + d] : noise[0];
        nodes[bn * DIMM + d] = nd;
    }
    float m   = block_reduce_sum_8w(own ? nd : 0.0f, s_red) * (1.0f / 128.0f);
    float df  = nd - m;
    float var = block_reduce_sum_8w(own ? df * df : 0.0f, s_red) * (1.0f / 128.0f);
    if (own) s_xn[d] = df * rsqrtf(var + 1e-5f) * ln1_g[d] + ln1_b[d];
    __syncthreads();

    qkv_staged_h(t, bn, 0, hWq, bq, hWkv, bkv, qb, hkb, hvb, s_xn, s_part, s_stage);
}

// Fused per-layer kernel: attention (fp16 k/v) + post pipeline (fp16 staged
// weights) + next-layer staged QKV. k/v double-buffered by layer parity.
__global__ __launch_bounds__(512, 2) void k_layer(int layer,
        const float* coords, const int* bonds,
        const float* We, const float* be,
        float* qb, const __half* hkin, const __half* hvin,
        __half* hkout, __half* hvout,
        const __half* hWo, const float* bo, const float* Wg1,
        const float* ln2_g, const float* ln2_b,
        const __half* hW1, const float* b1,
        const __half* hW2, const float* b2,
        const float* Wg2,
        const float* ln1_g, const float* ln1_b,
        const __half* hWq, const float* bq,
        const __half* hWkv, const float* bkv,
        float* nodes) {
    int bn = blockIdx.x;
    int b = bn >> 7, i = bn & 127;
    int t = threadIdx.x;
    int d = t & 127;
    bool own = (t < 128);

    __shared__ float scoord[3 * NN];
    __shared__ float sedge[3 * NN];
    __shared__ int   sadj[NN];
    __shared__ float s_o[4 * INNER];
    __shared__ float s_l[4 * HEADS];
    __shared__ float s_ao[INNER];
    __shared__ float s_h[INNER];
    __shared__ float s_xn[128];
    __shared__ float s_red[8];
    __shared__ float s_part[4096];
    __shared__ float s_stage[16384];
    float* buf0 = s_stage;
    float* buf1 = s_stage + 8192;

    const __half* WoL = hWo + (size_t)layer * INNER * DIMM;

    // ---------- Phase A: attention ----------
    int jg = t >> 7, c = t & 127, h = c >> 4;

    const float4* qR  = (const float4*)(qb + (size_t)bn * INNER);
    const float4* WeR = (const float4*)(We + (size_t)layer * 3 * INNER);
    float4 qv  = qR[c];
    float4 we0 = WeR[c], we1 = WeR[128 + c], we2 = WeR[256 + c];
    float4 bev = ((const float4*)(be + (size_t)layer * INNER))[c];
    float res = own ? nodes[bn * DIMM + d] : 0.0f;

    if (t < 3 * NN) scoord[t] = coords[b * 3 * NN + t];
    if (t < NN) sadj[t] = 0;
    __syncthreads();
    if (t < EE) {
        int e0 = bonds[2 * t], e1 = bonds[2 * t + 1];
        if (e0 == i) sadj[e1] = 1;
        if (e1 == i) sadj[e0] = 1;
    }
    __syncthreads();
    if (t < NN) {
        int j = t;
        float msk = sadj[j] ? 1.0f : 0.0f;
        sedge[3 * j + 0] = msk * (scoord[3 * i + 0] - scoord[3 * j + 0]);
        sedge[3 * j + 1] = msk * (scoord[3 * i + 1] - scoord[3 * j + 1]);
        sedge[3 * j + 2] = msk * (scoord[3 * i + 2] - scoord[3 * j + 2]);
    }
    __syncthreads();

    // overlap first Wo chunk DMA with the attention j-loop
    stage32kB(WoL, buf0);

    const float2* kR2 = (const float2*)(hkin + (size_t)b * NN * INNER);
    const float2* vR2 = (const float2*)(hvin + (size_t)b * NN * INNER);

    float l_run = 0.0f;
    float4 o_run = {0, 0, 0, 0};
    int j0 = jg * 32;
#pragma unroll
    for (int base = 0; base < 32; base += 8) {
        float2 kraw[8], vraw[8];
#pragma unroll
        for (int p = 0; p < 8; p++) {
            int j = j0 + base + p;
            kraw[p] = kR2[j * 128 + c];
            vraw[p] = vR2[j * 128 + c];
        }
#pragma unroll
        for (int p = 0; p < 8; p++) {
            int j = j0 + base + p;
            float ex = sedge[3 * j], ey = sedge[3 * j + 1], ez = sedge[3 * j + 2];
            float4 e;
            e.x = bev.x + ex * we0.x + ey * we1.x + ez * we2.x;
            e.y = bev.y + ex * we0.y + ey * we1.y + ez * we2.y;
            e.z = bev.z + ex * we0.z + ey * we1.z + ez * we2.z;
            e.w = bev.w + ex * we0.w + ey * we1.w + ez * we2.w;
            const __half2* kh = (const __half2*)&kraw[p];
            float2 k01 = __half22float2(kh[0]), k23 = __half22float2(kh[1]);
            float s = (qv.x * (k01.x + e.x) + qv.y * (k01.y + e.y))
                    + (qv.z * (k23.x + e.z) + qv.w * (k23.y + e.w));
            s += __shfl_xor(s, 1, 64);
            s += __shfl_xor(s, 2, 64);
            s += __shfl_xor(s, 4, 64);
            s += __shfl_xor(s, 8, 64);
            float pp = __expf(s * 0.125f);
            const __half2* vh = (const __half2*)&vraw[p];
            float2 v01 = __half22float2(vh[0]), v23 = __half22float2(vh[1]);
            l_run += pp;
            o_run.x += pp * (v01.x + e.x);
            o_run.y += pp * (v01.y + e.y);
            o_run.z += pp * (v23.x + e.z);
            o_run.w += pp * (v23.y + e.w);
        }
    }
    ((float4*)(s_o + jg * INNER))[c] = o_run;
    if ((c & 15) == 0) s_l[jg * HEADS + h] = l_run;
    __syncthreads();
    if (jg == 0) {
        float4 o = o_run;
        float l = l_run;
#pragma unroll
        for (int g = 1; g < 4; g++) {
            float4 og = ((float4*)(s_o + g * INNER))[c];
            o.x += og.x; o.y += og.y; o.z += og.z; o.w += og.w;
            l += s_l[g * HEADS + h];
        }
        float inv = 1.0f / l;
        float4 rr; rr.x = o.x * inv; rr.y = o.y * inv; rr.z = o.z * inv; rr.w = o.w * inv;
        ((float4*)s_ao)[c] = rr;
    }
    __syncthreads();

    // ---------- Phase B: post pipeline (fp16 staged weights) ----------
    int c5 = t & 31, kg16 = t >> 5;

    // Wo fp16: [512 x 128] = 128 KB = 4 chunks x 128 rows. kg16 owns 8 rows/chunk.
    {
        float4 acw = {0, 0, 0, 0};
        for (int cc = 0; cc < 4; cc++) {
            __syncthreads();
            if (cc < 3) stage32kB(WoL + (cc + 1) * 16384, (cc & 1) ? buf0 : buf1);
            const float2* w2 = (const float2*)((cc & 1) ? buf1 : buf0);
#pragma unroll
            for (int rr = 0; rr < 8; rr++) {
                int row = kg16 * 8 + rr;
                fma4h(acw, s_ao[cc * 128 + row], w2[row * 32 + c5]);
            }
        }
        ((float4*)(s_part + kg16 * 128))[c5] = acw;
    }
    __syncthreads();
    float x = 0.0f;
    if (own) {
        x = bo[layer * DIMM + d];
#pragma unroll
        for (int g = 0; g < 16; g++) x += s_part[g * 128 + d];
    }

    const float* Wg1_l = Wg1 + layer * 3 * DIMM;
    float texpr = own ? (x * Wg1_l[d] + res * Wg1_l[DIMM + d] + (x - res) * Wg1_l[2 * DIMM + d]) : 0.0f;
    float g1 = block_reduce_sum_8w(texpr, s_red);
    g1 = 1.0f / (1.0f + __expf(-g1));
    float n1 = x * g1 + res * (1.0f - g1);

    float m   = block_reduce_sum_8w(own ? n1 : 0.0f, s_red) * (1.0f / 128.0f);
    float df  = n1 - m;
    float var = block_reduce_sum_8w(own ? df * df : 0.0f, s_red) * (1.0f / 128.0f);
    float xn  = df * rsqrtf(var + 1e-5f) * ln2_g[layer * DIMM + d] + ln2_b[layer * DIMM + d];
    if (own) s_xn[d] = xn;

    // FF1 fp16: [128 x 512] = 128 KB = 4 chunks x 32 rows. kg4 owns 8 rows/chunk.
    int c7 = t & 127, kg4 = t >> 7;
    const __half* W1L = hW1 + (size_t)layer * DIMM * 4 * DIMM;
    stage32kB(W1L, buf0);
    {
        float4 ac1 = {0, 0, 0, 0};
        for (int cc = 0; cc < 4; cc++) {
            __syncthreads();
            if (cc < 3) stage32kB(W1L + (cc + 1) * 16384, (cc & 1) ? buf0 : buf1);
            const float2* w2 = (const float2*)((cc & 1) ? buf1 : buf0);
#pragma unroll
            for (int rr = 0; rr < 8; rr++) {
                int row = kg4 * 8 + rr;
                fma4h(ac1, s_xn[cc * 32 + row], w2[row * 128 + c7]);
            }
        }
        ((float4*)(s_part + kg4 * 512))[c7] = ac1;
    }
    __syncthreads();
    {
        float a = b1[layer * 4 * DIMM + t];
#pragma unroll
        for (int g = 0; g < 4; g++) a += s_part[g * 512 + t];
        a = 0.5f * a * (1.0f + erff(a * 0.70710678f));
        s_h[t] = a;
    }

    // FF2 fp16: [512 x 128], same shape as Wo. Input s_h.
    const __half* W2L = hW2 + (size_t)layer * 4 * DIMM * DIMM;
    stage32kB(W2L, buf0);
    {
        float4 ac2 = {0, 0, 0, 0};
        for (int cc = 0; cc < 4; cc++) {
            __syncthreads();
            if (cc < 3) stage32kB(W2L + (cc + 1) * 16384, (cc & 1) ? buf0 : buf1);
            const float2* w2 = (const float2*)((cc & 1) ? buf1 : buf0);
#pragma unroll
            for (int rr = 0; rr < 8; rr++) {
                int row = kg16 * 8 + rr;
                fma4h(ac2, s_h[cc * 128 + row], w2[row * 32 + c5]);
            }
        }
        ((float4*)(s_part + kg16 * 128))[c5] = ac2;
    }
    __syncthreads();
    float y = 0.0f;
    if (own) {
        y = b2[layer * DIMM + d];
#pragma unroll
        for (int g = 0; g < 16; g++) y += s_part[g * 128 + d];
    }

    const float* Wg2_l = Wg2 + layer * 3 * DIMM;
    texpr = own ? (y * Wg2_l[d] + n1 * Wg2_l[DIMM + d] + (y - n1) * Wg2_l[2 * DIMM + d]) : 0.0f;
    float g2 = block_reduce_sum_8w(texpr, s_red);
    g2 = 1.0f / (1.0f + __expf(-g2));
    float n2 = y * g2 + n1 * (1.0f - g2);
    if (own) nodes[bn * DIMM + d] = n2;

    if (layer < DEPTH - 1) {
        float m1   = block_reduce_sum_8w(own ? n2 : 0.0f, s_red) * (1.0f / 128.0f);
        float df1  = n2 - m1;
        float var1 = block_reduce_sum_8w(own ? df1 * df1 : 0.0f, s_red) * (1.0f / 128.0f);
        if (own) s_xn[d] = df1 * rsqrtf(var1 + 1e-5f) * ln1_g[(layer + 1) * DIMM + d]
                         + ln1_b[(layer + 1) * DIMM + d];
        __syncthreads();
        qkv_staged_h(t, bn, layer + 1, hWq, bq, hWkv, bkv, qb, hkout, hvout,
                     s_xn, s_part, s_stage);
    }
}

// Final: sum over nodes of (nodes @ Wlin + blin) -> scalar.
__global__ __launch_bounds__(256) void k_final(const float* nodes, const float* Wlin,
                                               const float* blin, float* out) {
    int t = threadIdx.x;
    __shared__ float s_w[DIMM];
    if (t < DIMM) s_w[t] = Wlin[t];
    __syncthreads();
    float s = blin[0];
    const float4* nr = (const float4*)(nodes + t * DIMM);
#pragma unroll 8
    for (int q = 0; q < 32; q++) {
        float4 n = nr[q];
        s += n.x * s_w[4 * q] + n.y * s_w[4 * q + 1] + n.z * s_w[4 * q + 2] + n.w * s_w[4 * q + 3];
    }
#pragma unroll
    for (int off = 32; off > 0; off >>= 1) s += __shfl_xor(s, off, 64);
    __shared__ float sb[4];
    int wave = t >> 6, lane = t & 63;
    if (lane == 0) sb[wave] = s;
    __syncthreads();
    if (t == 0) out[0] = sb[0] + sb[1] + sb[2] + sb[3];
}

extern "C" void kernel_launch(void* const* d_in, const int* in_sizes, int n_in,
                              void* d_out, int out_size, void* d_ws, size_t ws_size,
                              hipStream_t stream) {
    const int*   indices = (const int*)d_in[0];
    const float* coords  = (const float*)d_in[1];
    const int*   bonds   = (const int*)d_in[2];
    const float* noise   = (const float*)d_in[3];
    const float* atom_emb= (const float*)d_in[4];
    const float* ln1_g   = (const float*)d_in[5];
    const float* ln1_b   = (const float*)d_in[6];
    const float* Wq      = (const float*)d_in[7];
    const float* bq      = (const float*)d_in[8];
    const float* Wkv     = (const float*)d_in[9];
    const float* bkv     = (const float*)d_in[10];
    const float* We      = (const float*)d_in[11];
    const float* be      = (const float*)d_in[12];
    const float* Wo      = (const float*)d_in[13];
    const float* bo      = (const float*)d_in[14];
    const float* Wg1     = (const float*)d_in[15];
    const float* ln2_g   = (const float*)d_in[16];
    const float* ln2_b   = (const float*)d_in[17];
    const float* W1      = (const float*)d_in[18];
    const float* b1      = (const float*)d_in[19];
    const float* W2      = (const float*)d_in[20];
    const float* b2      = (const float*)d_in[21];
    const float* Wg2     = (const float*)d_in[22];
    const float* Wlin    = (const float*)d_in[23];
    const float* blin    = (const float*)d_in[24];

    float*  ws    = (float*)d_ws;
    float*  nodes = ws;                         // 32768 f
    float*  qb    = nodes + NNODE * DIMM;       // 131072 f
    __half* hkb   = (__half*)(qb + NNODE * INNER);  // 2 slabs x 131072 halves
    __half* hvb   = hkb + 2 * NNODE * INNER;
    __half* hWq   = hvb + 2 * NNODE * INNER;    // 393216 halves
    __half* hWkv  = hWq + 393216;               // 786432
    __half* hWo   = hWkv + 786432;              // 393216
    __half* hW1   = hWo + 393216;
    __half* hW2   = hW1 + 393216;

    k_cvt<<<1152, 512, 0, stream>>>(Wq, Wkv, Wo, W1, W2, hWq, hWkv, hWo, hW1, hW2);
    k_pre<<<NNODE, 512, 0, stream>>>(indices, noise, atom_emb, ln1_g, ln1_b,
                                     hWq, bq, hWkv, bkv, nodes, qb, hkb, hvb);
    for (int l = 0; l < DEPTH; l++) {
        const __half* hkin = hkb + (size_t)(l & 1) * NNODE * INNER;
        const __half* hvin = hvb + (size_t)(l & 1) * NNODE * INNER;
        __half* hkout = hkb + (size_t)((l + 1) & 1) * NNODE * INNER;
        __half* hvout = hvb + (size_t)((l + 1) & 1) * NNODE * INNER;
        k_layer<<<NNODE, 512, 0, stream>>>(l, coords, bonds, We, be,
                                           qb, hkin, hvin, hkout, hvout,
                                           hWo, bo, Wg1, ln2_g, ln2_b, hW1, b1, hW2, b2,
                                           Wg2, ln1_g, ln1_b, hWq, bq, hWkv, bkv, nodes);
    }
    k_final<<<1, 256, 0, stream>>>(nodes, Wlin, blin, (float*)d_out);
}